// Round 5
// baseline (8014.034 us; speedup 1.0000x reference)
//
#include <hip/hip_runtime.h>

// EQL network: 5-layer MLP + envelope argmax.
// Precision: f16 two-way split (hi/lo), 3 MFMAs per product (hh+hl+lh), 2^11
// pre-scale per operand -> ~2^-21 effective input precision, fp32 accumulate.
// R4 -> R5: MFMA density. R4 profile showed MFMA (768 cyc) : LDS port (768
// cyc) exactly balanced per CU K-step -> conflict fix couldn't help. Block
// tile 128x128 -> 256x128, wave tile 64x64 -> 128x64 (4x2 frags): 48 MFMA per
// 24 ds_reads per wave (ratio 1.5 -> 2.0), staged bytes per MFMA -25%.
// LDS 48 KB: Ahi/Alo 256x32, Bhi/Blo 128x32. Swizzle unchanged:
// slot = 4r + (g ^ ((r>>1)&3)) covers all 8 bank groups per half-wave.

#define AS1 __attribute__((address_space(1)))
#define AS3 __attribute__((address_space(3)))

typedef _Float16 half8 __attribute__((ext_vector_type(8)));
typedef float floatx16 __attribute__((ext_vector_type(16)));

static constexpr float SCALE = 2048.0f;                         // 2^11
static constexpr float INV_SCALE2 = 1.0f / (2048.0f * 2048.0f); // 2^-22

// -------------------------------------------------- weight split (strided src)
__global__ void split_w_kernel(const float* __restrict__ src, _Float16* __restrict__ hi,
                               _Float16* __restrict__ lo, int srcStride, int colOff,
                               int Kcopy, int Kpad) {
  int k = blockIdx.x * 256 + threadIdx.x;
  int n = blockIdx.y;
  if (k >= Kpad) return;
  float v = (k < Kcopy) ? src[(size_t)n * srcStride + colOff + k] * SCALE : 0.0f;
  _Float16 h = (_Float16)v;
  _Float16 l = (_Float16)(v - (float)h);
  size_t o = (size_t)n * Kpad + k;
  hi[o] = h;
  lo[o] = l;
}

// ------------------------------------------------------- x prep (concat+split)
__global__ void prep_x_kernel(const float* __restrict__ state, const float* __restrict__ pref,
                              _Float16* __restrict__ hi, _Float16* __restrict__ lo) {
  int k = threadIdx.x;
  int b = blockIdx.x;
  if (k >= 160) return;
  float v = 0.0f;
  if (k < 128) v = state[(size_t)b * 128 + k];
  else if (k < 132) v = pref[(size_t)b * 4 + (k - 128)];
  v *= SCALE;
  _Float16 h = (_Float16)v;
  _Float16 l = (_Float16)(v - (float)h);
  size_t o = (size_t)b * 160 + k;
  hi[o] = h;
  lo[o] = l;
}

// ------------------------------------------------------------ split-3 MFMA GEMM
// C[m][n] = sum_k A[m][k]*B[n][k]  (both K-contiguous). Tile 256x128xBK32,
// 256 thr = 4 waves (2x2 wave grid), wave = 128x64 via 4x2 frags of
// v_mfma_f32_32x32x16_f16. LDS 48 KB: Ahi[0,16K) Alo[16K,32K) Bhi[32K,40K)
// Blo[40K,48K) bytes; logical (row r, granule g) at slot 4r + (g^((r>>1)&3)).
// K range per block: [blockIdx.z*kPerZ, +kPerZ).
// mode 0: Ohi/Olo = split( relu(acc*2^-22 + bias[col]) * 2^11 )
// mode 1: Oacc[(bz*Mrows+row)*N+col] = acc*2^-22 (+ old if accAdd)
// mode 2: v = acc*2^-22 + Oacc[row*N+col]; Ohi/Olo = split(relu(v+bias)*2^11)
__global__ __launch_bounds__(256) void gemm3_kernel(
    const _Float16* __restrict__ Ahi, const _Float16* __restrict__ Alo,
    const _Float16* __restrict__ Bhi, const _Float16* __restrict__ Blo,
    const float* __restrict__ bias,
    _Float16* __restrict__ Ohi, _Float16* __restrict__ Olo,
    float* __restrict__ Oacc,
    int K, int N, int kPerZ, int mode, int accAdd, int Mrows) {
  __shared__ _Float16 lds[24576];  // 48 KB
  const int tid = threadIdx.x;
  const int wave = tid >> 6;
  const int lane = tid & 63;
  const int m0 = blockIdx.x * 256;
  const int n0 = blockIdx.y * 128;
  const int kBeg = blockIdx.z * kPerZ;

  // 12 staging issues/thread over 3072 16B slots:
  // slots [0,1024) Ahi, [1024,2048) Alo, [2048,2560) Bhi, [2560,3072) Blo.
  // Physical slot p holds logical (r = p'>>2, g = (p'&3)^((r>>1)&3)).
  const _Float16* gp[12];
  int loff[12];
#pragma unroll
  for (int j = 0; j < 12; ++j) {
    const int p = (j << 8) + (wave << 6) + lane;
    const _Float16* plane;
    int row, g;
    if (p < 2048) {
      int pl = p & 1023;
      int r = pl >> 2;
      g = (pl & 3) ^ ((r >> 1) & 3);
      row = m0 + r;  // Mc always a multiple of 256
      plane = (p >> 10) ? Alo : Ahi;
    } else {
      int pb = p - 2048;
      int pl = pb & 511;
      int r = pl >> 2;
      g = (pl & 3) ^ ((r >> 1) & 3);
      row = n0 + r;
      if (row > N - 1) row = N - 1;  // tail N-tile: clamp (cols guarded at write)
      plane = (pb >> 9) ? Blo : Bhi;
    }
    gp[j] = plane + (size_t)row * K + kBeg + 8 * g;
    loff[j] = ((j << 8) + (wave << 6)) * 8;  // wave-uniform base (halfs)
  }

  const int wm = wave >> 1, wn = wave & 1;
  floatx16 acc[4][2];
#pragma unroll
  for (int i = 0; i < 4; ++i)
#pragma unroll
    for (int j = 0; j < 2; ++j)
#pragma unroll
      for (int e = 0; e < 16; ++e) acc[i][j][e] = 0.0f;

  const int gHalf = lane >> 5;
  const int lane31 = lane & 31;

  const int nSteps = kPerZ >> 5;
  for (int ks = 0; ks < nSteps; ++ks) {
    __syncthreads();
#pragma unroll
    for (int j = 0; j < 12; ++j) {
      __builtin_amdgcn_global_load_lds((const AS1 unsigned int*)gp[j],
                                       (AS3 unsigned int*)&lds[loff[j]], 16, 0, 0);
      gp[j] += 32;
    }
    __syncthreads();  // implies vmcnt(0) drain -> staged data visible
#pragma unroll
    for (int kh = 0; kh < 2; ++kh) {
      half8 ah[4], al[4], bh[2], bl[2];
      const int gg = (kh << 1) + gHalf;
#pragma unroll
      for (int j = 0; j < 2; ++j) {
        int rB = (wn << 6) + (j << 5) + lane31;
        int sB = (rB << 2) + (gg ^ ((rB >> 1) & 3));
        bh[j] = *(const half8*)&lds[16384 + (sB << 3)];
        bl[j] = *(const half8*)&lds[20480 + (sB << 3)];
      }
#pragma unroll
      for (int i = 0; i < 4; ++i) {
        int rA = (wm << 7) + (i << 5) + lane31;
        int sA = (rA << 2) + (gg ^ ((rA >> 1) & 3));
        ah[i] = *(const half8*)&lds[sA << 3];
        al[i] = *(const half8*)&lds[8192 + (sA << 3)];
      }
#pragma unroll
      for (int i = 0; i < 4; ++i)
#pragma unroll
        for (int j = 0; j < 2; ++j) {
          acc[i][j] = __builtin_amdgcn_mfma_f32_32x32x16_f16(ah[i], bh[j], acc[i][j], 0, 0, 0);
          acc[i][j] = __builtin_amdgcn_mfma_f32_32x32x16_f16(ah[i], bl[j], acc[i][j], 0, 0, 0);
          acc[i][j] = __builtin_amdgcn_mfma_f32_32x32x16_f16(al[i], bh[j], acc[i][j], 0, 0, 0);
        }
    }
  }

  // C/D layout: col = lane&31, row = (e&3) + 8*(e>>2) + 4*(lane>>5)  [m74/m101]
#pragma unroll
  for (int i = 0; i < 4; ++i)
#pragma unroll
    for (int j = 0; j < 2; ++j)
#pragma unroll
      for (int e = 0; e < 16; ++e) {
        int row = m0 + (wm << 7) + (i << 5) + ((e & 3) + ((e >> 2) << 3) + ((lane >> 5) << 2));
        int col = n0 + (wn << 6) + (j << 5) + lane31;
        if (col < N) {
          float v = acc[i][j][e] * INV_SCALE2;
          if (mode == 0) {
            size_t o = (size_t)row * N + col;
            v = fmaxf(v + bias[col], 0.0f) * SCALE;
            _Float16 h = (_Float16)v;
            _Float16 l = (_Float16)(v - (float)h);
            Ohi[o] = h;
            Olo[o] = l;
          } else if (mode == 1) {
            size_t o = ((size_t)blockIdx.z * Mrows + row) * N + col;
            if (accAdd) v += Oacc[o];
            Oacc[o] = v;
          } else {  // mode 2: finalize L4 -> split H4 planes
            size_t o = (size_t)row * N + col;
            v += Oacc[o];
            v = fmaxf(v + bias[col], 0.0f) * SCALE;
            _Float16 h = (_Float16)v;
            _Float16 l = (_Float16)(v - (float)h);
            Ohi[o] = h;
            Olo[o] = l;
          }
        }
      }
}

// --------------------------------- reduce split-K partials + envelope argmax
// One thread per row. QP layout [12][Mc][64] fp32.
__global__ __launch_bounds__(128) void finish_kernel(
    const float* __restrict__ part, const float* __restrict__ bq,
    const float* __restrict__ pref, float* __restrict__ out, int rowBase, int Mc) {
  int b = blockIdx.x * 128 + threadIdx.x;  // chunk-local row
  if (b >= Mc) return;
  float q[64];
#pragma unroll
  for (int o4 = 0; o4 < 16; ++o4) {
    float4 bb = *(const float4*)&bq[o4 * 4];
    q[o4 * 4 + 0] = bb.x;
    q[o4 * 4 + 1] = bb.y;
    q[o4 * 4 + 2] = bb.z;
    q[o4 * 4 + 3] = bb.w;
  }
  for (int z = 0; z < 12; ++z) {
    const float* pz = &part[(size_t)(z * Mc + b) * 64];
#pragma unroll
    for (int o4 = 0; o4 < 16; ++o4) {
      float4 s = *(const float4*)&pz[o4 * 4];
      q[o4 * 4 + 0] += s.x;
      q[o4 * 4 + 1] += s.y;
      q[o4 * 4 + 2] += s.z;
      q[o4 * 4 + 3] += s.w;
    }
  }
  int g = rowBase + b;
  float* qout = out + 32768 + (size_t)g * 64;
#pragma unroll
  for (int o4 = 0; o4 < 16; ++o4)
    *(float4*)&qout[o4 * 4] = make_float4(q[o4 * 4], q[o4 * 4 + 1], q[o4 * 4 + 2], q[o4 * 4 + 3]);
  float p0 = pref[(size_t)g * 4 + 0], p1 = pref[(size_t)g * 4 + 1];
  float p2 = pref[(size_t)g * 4 + 2], p3 = pref[(size_t)g * 4 + 3];
  float best = q[0] * p0 + q[1] * p1 + q[2] * p2 + q[3] * p3;
  int ba = 0;
#pragma unroll
  for (int a = 1; a < 16; ++a) {
    float ip = q[4 * a] * p0 + q[4 * a + 1] * p1 + q[4 * a + 2] * p2 + q[4 * a + 3] * p3;
    if (ip > best) { best = ip; ba = a; }  // strict > == first-tie jnp.argmax
  }
  *(float4*)&out[(size_t)g * 4] =
      make_float4(q[4 * ba], q[4 * ba + 1], q[4 * ba + 2], q[4 * ba + 3]);
}

// ------------------------------------------------------------------- launcher
extern "C" void kernel_launch(void* const* d_in, const int* in_sizes, int n_in,
                              void* d_out, int out_size, void* d_ws, size_t ws_size,
                              hipStream_t stream) {
  const float* state = (const float*)d_in[0];
  const float* pref = (const float*)d_in[1];
  const float* w1 = (const float*)d_in[2];
  const float* b1 = (const float*)d_in[3];
  const float* w2 = (const float*)d_in[4];
  const float* b2 = (const float*)d_in[5];
  const float* w3 = (const float*)d_in[6];
  const float* b3 = (const float*)d_in[7];
  const float* w4 = (const float*)d_in[8];
  const float* b4 = (const float*)d_in[9];
  const float* wq = (const float*)d_in[10];
  const float* bq = (const float*)d_in[11];

  char* ws = (char*)d_ws;
  size_t off = 0;
  auto take = [&](size_t bytes) {
    size_t r = off;
    off += (bytes + 255) & ~(size_t)255;
    return r;
  };
  const size_t oW1h = take((size_t)2112 * 160 * 2);
  const size_t oW1l = take((size_t)2112 * 160 * 2);
  const size_t oW2h = take((size_t)4224 * 2112 * 2);
  const size_t oW2l = take((size_t)4224 * 2112 * 2);
  const size_t oW3h = take((size_t)2112 * 4224 * 2);  // quarter N-chunk of W3
  const size_t oW3l = take((size_t)2112 * 4224 * 2);
  const size_t oW4h = take((size_t)4224 * 2112 * 2);  // quarter K-slice of W4
  const size_t oW4l = take((size_t)4224 * 2112 * 2);
  const size_t oW5h = take((size_t)64 * 4224 * 2);
  const size_t oW5l = take((size_t)64 * 4224 * 2);
  const size_t fixed = off;

  // per-row bytes: X 640 + H1 8448 + H2 16896 + H3 8448 + ACC 16896 = 51328
  // (H4 overlays H2; QP overlays H1: 12*64*4 = 3072 B/row < 8448)
  int Mc = 8192;
  while (Mc > 256 && fixed + (size_t)Mc * 51328 + 4096 > ws_size) Mc >>= 1;

  const size_t oXh = take((size_t)Mc * 160 * 2);
  const size_t oXl = take((size_t)Mc * 160 * 2);
  const size_t oH1h = take((size_t)Mc * 2112 * 2);
  const size_t oH1l = take((size_t)Mc * 2112 * 2);
  const size_t oH2h = take((size_t)Mc * 4224 * 2);
  const size_t oH2l = take((size_t)Mc * 4224 * 2);
  const size_t oH3h = take((size_t)Mc * 2112 * 2);
  const size_t oH3l = take((size_t)Mc * 2112 * 2);
  const size_t oACC = take((size_t)Mc * 4224 * 4);

  _Float16* W1h = (_Float16*)(ws + oW1h);
  _Float16* W1l = (_Float16*)(ws + oW1l);
  _Float16* W2h = (_Float16*)(ws + oW2h);
  _Float16* W2l = (_Float16*)(ws + oW2l);
  _Float16* W3h = (_Float16*)(ws + oW3h);
  _Float16* W3l = (_Float16*)(ws + oW3l);
  _Float16* W4h = (_Float16*)(ws + oW4h);
  _Float16* W4l = (_Float16*)(ws + oW4l);
  _Float16* W5h = (_Float16*)(ws + oW5h);
  _Float16* W5l = (_Float16*)(ws + oW5l);
  _Float16* Xh = (_Float16*)(ws + oXh);
  _Float16* Xl = (_Float16*)(ws + oXl);
  _Float16* H1h = (_Float16*)(ws + oH1h);
  _Float16* H1l = (_Float16*)(ws + oH1l);
  _Float16* H2h = (_Float16*)(ws + oH2h);
  _Float16* H2l = (_Float16*)(ws + oH2l);
  _Float16* H3h = (_Float16*)(ws + oH3h);
  _Float16* H3l = (_Float16*)(ws + oH3l);
  float* ACC = (float*)(ws + oACC);
  _Float16* H4h = H2h;              // overlays H2 (dead after last L3)
  _Float16* H4l = H2l;
  float* QP = (float*)(ws + oH1h);  // overlays H1 (dead after L2)

  // persistent weight splits (W1 padded 132->160)
  split_w_kernel<<<dim3(1, 2112), 256, 0, stream>>>(w1, W1h, W1l, 132, 0, 132, 160);
  split_w_kernel<<<dim3(9, 4224), 256, 0, stream>>>(w2, W2h, W2l, 2112, 0, 2112, 2112);
  split_w_kernel<<<dim3(17, 64), 256, 0, stream>>>(wq, W5h, W5l, 4224, 0, 4224, 4224);

  const int NC = 8192 / Mc;
  const int GX = Mc / 256;
  for (int mc = 0; mc < NC; ++mc) {
    const float* st = state + (size_t)mc * Mc * 128;
    const float* pf = pref + (size_t)mc * Mc * 4;
    prep_x_kernel<<<dim3(Mc), 192, 0, stream>>>(st, pf, Xh, Xl);
    // L1: [Mc,160] x [2112,160]
    gemm3_kernel<<<dim3(GX, 17), 256, 0, stream>>>(Xh, Xl, W1h, W1l, b1, H1h, H1l,
                                                   nullptr, 160, 2112, 160, 0, 0, Mc);
    // L2: K=2112 -> N=4224
    gemm3_kernel<<<dim3(GX, 33), 256, 0, stream>>>(H1h, H1l, W2h, W2l, b2, H2h, H2l,
                                                   nullptr, 2112, 4224, 2112, 0, 0, Mc);
    // L3/L4 fused over 4 N-chunks of H3 (2112 each); ACC accumulates L4;
    // last chunk finalizes relu+b4 and writes split H4 planes (over H2).
    for (int c = 0; c < 4; ++c) {
      split_w_kernel<<<dim3(17, 2112), 256, 0, stream>>>(w3 + (size_t)c * 2112 * 4224, W3h,
                                                         W3l, 4224, 0, 4224, 4224);
      split_w_kernel<<<dim3(9, 4224), 256, 0, stream>>>(w4, W4h, W4l, 8448, c * 2112, 2112,
                                                        2112);
      gemm3_kernel<<<dim3(GX, 17), 256, 0, stream>>>(H2h, H2l, W3h, W3l, b3 + c * 2112,
                                                     H3h, H3l, nullptr, 4224, 2112, 4224,
                                                     0, 0, Mc);
      if (c < 3) {
        gemm3_kernel<<<dim3(GX, 33), 256, 0, stream>>>(H3h, H3l, W4h, W4l, nullptr, nullptr,
                                                       nullptr, ACC, 2112, 4224, 2112, 1,
                                                       c > 0 ? 1 : 0, Mc);
      } else {
        gemm3_kernel<<<dim3(GX, 33), 256, 0, stream>>>(H3h, H3l, W4h, W4l, b4, H4h, H4l,
                                                       ACC, 2112, 4224, 2112, 2, 0, Mc);
      }
    }
    // L5: [Mc,4224] x [64,4224], split-K=12 (kPerZ=352) -> QP fp32 partials
    gemm3_kernel<<<dim3(GX, 1, 12), 256, 0, stream>>>(H4h, H4l, W5h, W5l, nullptr, nullptr,
                                                      nullptr, QP, 4224, 64, 352, 1, 0, Mc);
    // reduce partials + bq, write q, envelope argmax -> hq
    finish_kernel<<<dim3(Mc / 128), 128, 0, stream>>>(QP, bq, pref, (float*)d_out,
                                                      mc * Mc, Mc);
  }
}

// Round 6
// 6005.366 us; speedup vs baseline: 1.3345x; 1.3345x over previous
//
#include <hip/hip_runtime.h>

// EQL network: 5-layer MLP + envelope argmax.
// Precision: f16 two-way split (hi/lo), 3 MFMAs per product (hh+hl+lh), 2^11
// pre-scale per operand -> ~2^-21 effective input precision, fp32 accumulate.
// R5 -> R6: occupancy fix. R5's 256x128 tile spent 144 VGPR + 128 AGPR =
// 272 regs/wave -> 1 wave/SIMD -> 1 block/CU -> serialized K-loop (MfmaUtil
// 17%, occupancy 10%). Same tile, but: (1) staging pointers compressed from
// 12x64b VGPR pairs to 6x32b byte offsets against SGPR plane bases (saddr
// form), (2) A-operands loaded per-i inside the MFMA loop (24 live operand
// VGPRs instead of 48), (3) __launch_bounds__(256,2) pins 2 waves/EU ->
// 2 blocks/CU -> cross-block overlap of staging/drain under MFMA.

#define AS1 __attribute__((address_space(1)))
#define AS3 __attribute__((address_space(3)))

typedef _Float16 half8 __attribute__((ext_vector_type(8)));
typedef float floatx16 __attribute__((ext_vector_type(16)));

static constexpr float SCALE = 2048.0f;                         // 2^11
static constexpr float INV_SCALE2 = 1.0f / (2048.0f * 2048.0f); // 2^-22

// -------------------------------------------------- weight split (strided src)
__global__ void split_w_kernel(const float* __restrict__ src, _Float16* __restrict__ hi,
                               _Float16* __restrict__ lo, int srcStride, int colOff,
                               int Kcopy, int Kpad) {
  int k = blockIdx.x * 256 + threadIdx.x;
  int n = blockIdx.y;
  if (k >= Kpad) return;
  float v = (k < Kcopy) ? src[(size_t)n * srcStride + colOff + k] * SCALE : 0.0f;
  _Float16 h = (_Float16)v;
  _Float16 l = (_Float16)(v - (float)h);
  size_t o = (size_t)n * Kpad + k;
  hi[o] = h;
  lo[o] = l;
}

// ------------------------------------------------------- x prep (concat+split)
__global__ void prep_x_kernel(const float* __restrict__ state, const float* __restrict__ pref,
                              _Float16* __restrict__ hi, _Float16* __restrict__ lo) {
  int k = threadIdx.x;
  int b = blockIdx.x;
  if (k >= 160) return;
  float v = 0.0f;
  if (k < 128) v = state[(size_t)b * 128 + k];
  else if (k < 132) v = pref[(size_t)b * 4 + (k - 128)];
  v *= SCALE;
  _Float16 h = (_Float16)v;
  _Float16 l = (_Float16)(v - (float)h);
  size_t o = (size_t)b * 160 + k;
  hi[o] = h;
  lo[o] = l;
}

// ------------------------------------------------------------ split-3 MFMA GEMM
// C[m][n] = sum_k A[m][k]*B[n][k]  (both K-contiguous). Tile 256x128xBK32,
// 256 thr = 4 waves (2x2 wave grid), wave = 128x64 via 4x2 frags of
// v_mfma_f32_32x32x16_f16. LDS 48 KB (halfs): Ahi [0,8192) Alo [8192,16384)
// Bhi [16384,20480) Blo [20480,24576); logical (row r, granule g) at slot
// 4r + (g^((r>>1)&3)) within its plane. K range: [blockIdx.z*kPerZ, +kPerZ).
// mode 0: Ohi/Olo = split( relu(acc*2^-22 + bias[col]) * 2^11 )
// mode 1: Oacc[(bz*Mrows+row)*N+col] = acc*2^-22 (+ old if accAdd)
// mode 2: v = acc*2^-22 + Oacc[row*N+col]; Ohi/Olo = split(relu(v+bias)*2^11)
__global__ __launch_bounds__(256, 2) void gemm3_kernel(
    const _Float16* __restrict__ Ahi, const _Float16* __restrict__ Alo,
    const _Float16* __restrict__ Bhi, const _Float16* __restrict__ Blo,
    const float* __restrict__ bias,
    _Float16* __restrict__ Ohi, _Float16* __restrict__ Olo,
    float* __restrict__ Oacc,
    int K, int N, int kPerZ, int mode, int accAdd, int Mrows) {
  __shared__ _Float16 lds[24576];  // 48 KB
  const int tid = threadIdx.x;
  const int wave = tid >> 6;
  const int lane = tid & 63;
  const int m0 = blockIdx.x * 256;
  const int n0 = blockIdx.y * 128;
  const int kBeg = blockIdx.z * kPerZ;

  // Staging: 12 issues/thread = {Ahi,Alo}x4 + {Bhi,Blo}x2, driven by 6x32-bit
  // byte offsets (plane base stays in SGPRs -> saddr form, 1 VGPR per offset).
  // A issue j covers slots [j*256, j*256+256) of the 1024-slot A plane;
  // B issue j covers slots [j*256, +256) of the 512-slot B plane.
  unsigned offA[4], offB[2];
#pragma unroll
  for (int j = 0; j < 4; ++j) {
    const int p = (j << 8) + (wave << 6) + lane;
    const int r = p >> 2;
    const int g = (p & 3) ^ ((r >> 1) & 3);
    offA[j] = (unsigned)((((m0 + r) * (size_t)K) + kBeg + 8 * g) * 2);
  }
#pragma unroll
  for (int j = 0; j < 2; ++j) {
    const int p = (j << 8) + (wave << 6) + lane;
    const int r = p >> 2;
    const int g = (p & 3) ^ ((r >> 1) & 3);
    int row = n0 + r;
    if (row > N - 1) row = N - 1;  // tail N-tile: clamp (cols guarded at write)
    offB[j] = (unsigned)(((row * (size_t)K) + kBeg + 8 * g) * 2);
  }

  const int wm = wave >> 1, wn = wave & 1;
  floatx16 acc[4][2];
#pragma unroll
  for (int i = 0; i < 4; ++i)
#pragma unroll
    for (int j = 0; j < 2; ++j)
#pragma unroll
      for (int e = 0; e < 16; ++e) acc[i][j][e] = 0.0f;

  const int gHalf = lane >> 5;
  const int lane31 = lane & 31;

  const int nSteps = kPerZ >> 5;
  for (int ks = 0; ks < nSteps; ++ks) {
    __syncthreads();
#pragma unroll
    for (int j = 0; j < 4; ++j) {
      const int lo = ((j << 8) + (wave << 6)) * 8;  // wave-uniform half index
      __builtin_amdgcn_global_load_lds(
          (const AS1 unsigned int*)((const AS1 char*)Ahi + offA[j]),
          (AS3 unsigned int*)&lds[lo], 16, 0, 0);
      __builtin_amdgcn_global_load_lds(
          (const AS1 unsigned int*)((const AS1 char*)Alo + offA[j]),
          (AS3 unsigned int*)&lds[8192 + lo], 16, 0, 0);
      offA[j] += 64;
    }
#pragma unroll
    for (int j = 0; j < 2; ++j) {
      const int lo = ((j << 8) + (wave << 6)) * 8;
      __builtin_amdgcn_global_load_lds(
          (const AS1 unsigned int*)((const AS1 char*)Bhi + offB[j]),
          (AS3 unsigned int*)&lds[16384 + lo], 16, 0, 0);
      __builtin_amdgcn_global_load_lds(
          (const AS1 unsigned int*)((const AS1 char*)Blo + offB[j]),
          (AS3 unsigned int*)&lds[20480 + lo], 16, 0, 0);
      offB[j] += 64;
    }
    __syncthreads();  // implies vmcnt(0) drain -> staged data visible
#pragma unroll
    for (int kh = 0; kh < 2; ++kh) {
      const int gg = (kh << 1) + gHalf;
      half8 bh[2], bl[2];
#pragma unroll
      for (int j = 0; j < 2; ++j) {
        int rB = (wn << 6) + (j << 5) + lane31;
        int sB = (rB << 2) + (gg ^ ((rB >> 1) & 3));
        bh[j] = *(const half8*)&lds[16384 + (sB << 3)];
        bl[j] = *(const half8*)&lds[20480 + (sB << 3)];
      }
#pragma unroll
      for (int i = 0; i < 4; ++i) {
        int rA = (wm << 7) + (i << 5) + lane31;
        int sA = (rA << 2) + (gg ^ ((rA >> 1) & 3));
        half8 ah = *(const half8*)&lds[sA << 3];
        half8 al = *(const half8*)&lds[8192 + (sA << 3)];
#pragma unroll
        for (int j = 0; j < 2; ++j) {
          acc[i][j] = __builtin_amdgcn_mfma_f32_32x32x16_f16(ah, bh[j], acc[i][j], 0, 0, 0);
          acc[i][j] = __builtin_amdgcn_mfma_f32_32x32x16_f16(ah, bl[j], acc[i][j], 0, 0, 0);
          acc[i][j] = __builtin_amdgcn_mfma_f32_32x32x16_f16(al, bh[j], acc[i][j], 0, 0, 0);
        }
      }
    }
  }

  // C/D layout: col = lane&31, row = (e&3) + 8*(e>>2) + 4*(lane>>5)  [m74/m101]
#pragma unroll
  for (int i = 0; i < 4; ++i)
#pragma unroll
    for (int j = 0; j < 2; ++j)
#pragma unroll
      for (int e = 0; e < 16; ++e) {
        int row = m0 + (wm << 7) + (i << 5) + ((e & 3) + ((e >> 2) << 3) + ((lane >> 5) << 2));
        int col = n0 + (wn << 6) + (j << 5) + lane31;
        if (col < N) {
          float v = acc[i][j][e] * INV_SCALE2;
          if (mode == 0) {
            size_t o = (size_t)row * N + col;
            v = fmaxf(v + bias[col], 0.0f) * SCALE;
            _Float16 h = (_Float16)v;
            _Float16 l = (_Float16)(v - (float)h);
            Ohi[o] = h;
            Olo[o] = l;
          } else if (mode == 1) {
            size_t o = ((size_t)blockIdx.z * Mrows + row) * N + col;
            if (accAdd) v += Oacc[o];
            Oacc[o] = v;
          } else {  // mode 2: finalize L4 -> split H4 planes
            size_t o = (size_t)row * N + col;
            v += Oacc[o];
            v = fmaxf(v + bias[col], 0.0f) * SCALE;
            _Float16 h = (_Float16)v;
            _Float16 l = (_Float16)(v - (float)h);
            Ohi[o] = h;
            Olo[o] = l;
          }
        }
      }
}

// --------------------------------- reduce split-K partials + envelope argmax
// One thread per row. QP layout [12][Mc][64] fp32.
__global__ __launch_bounds__(128) void finish_kernel(
    const float* __restrict__ part, const float* __restrict__ bq,
    const float* __restrict__ pref, float* __restrict__ out, int rowBase, int Mc) {
  int b = blockIdx.x * 128 + threadIdx.x;  // chunk-local row
  if (b >= Mc) return;
  float q[64];
#pragma unroll
  for (int o4 = 0; o4 < 16; ++o4) {
    float4 bb = *(const float4*)&bq[o4 * 4];
    q[o4 * 4 + 0] = bb.x;
    q[o4 * 4 + 1] = bb.y;
    q[o4 * 4 + 2] = bb.z;
    q[o4 * 4 + 3] = bb.w;
  }
  for (int z = 0; z < 12; ++z) {
    const float* pz = &part[(size_t)(z * Mc + b) * 64];
#pragma unroll
    for (int o4 = 0; o4 < 16; ++o4) {
      float4 s = *(const float4*)&pz[o4 * 4];
      q[o4 * 4 + 0] += s.x;
      q[o4 * 4 + 1] += s.y;
      q[o4 * 4 + 2] += s.z;
      q[o4 * 4 + 3] += s.w;
    }
  }
  int g = rowBase + b;
  float* qout = out + 32768 + (size_t)g * 64;
#pragma unroll
  for (int o4 = 0; o4 < 16; ++o4)
    *(float4*)&qout[o4 * 4] = make_float4(q[o4 * 4], q[o4 * 4 + 1], q[o4 * 4 + 2], q[o4 * 4 + 3]);
  float p0 = pref[(size_t)g * 4 + 0], p1 = pref[(size_t)g * 4 + 1];
  float p2 = pref[(size_t)g * 4 + 2], p3 = pref[(size_t)g * 4 + 3];
  float best = q[0] * p0 + q[1] * p1 + q[2] * p2 + q[3] * p3;
  int ba = 0;
#pragma unroll
  for (int a = 1; a < 16; ++a) {
    float ip = q[4 * a] * p0 + q[4 * a + 1] * p1 + q[4 * a + 2] * p2 + q[4 * a + 3] * p3;
    if (ip > best) { best = ip; ba = a; }  // strict > == first-tie jnp.argmax
  }
  *(float4*)&out[(size_t)g * 4] =
      make_float4(q[4 * ba], q[4 * ba + 1], q[4 * ba + 2], q[4 * ba + 3]);
}

// ------------------------------------------------------------------- launcher
extern "C" void kernel_launch(void* const* d_in, const int* in_sizes, int n_in,
                              void* d_out, int out_size, void* d_ws, size_t ws_size,
                              hipStream_t stream) {
  const float* state = (const float*)d_in[0];
  const float* pref = (const float*)d_in[1];
  const float* w1 = (const float*)d_in[2];
  const float* b1 = (const float*)d_in[3];
  const float* w2 = (const float*)d_in[4];
  const float* b2 = (const float*)d_in[5];
  const float* w3 = (const float*)d_in[6];
  const float* b3 = (const float*)d_in[7];
  const float* w4 = (const float*)d_in[8];
  const float* b4 = (const float*)d_in[9];
  const float* wq = (const float*)d_in[10];
  const float* bq = (const float*)d_in[11];

  char* ws = (char*)d_ws;
  size_t off = 0;
  auto take = [&](size_t bytes) {
    size_t r = off;
    off += (bytes + 255) & ~(size_t)255;
    return r;
  };
  const size_t oW1h = take((size_t)2112 * 160 * 2);
  const size_t oW1l = take((size_t)2112 * 160 * 2);
  const size_t oW2h = take((size_t)4224 * 2112 * 2);
  const size_t oW2l = take((size_t)4224 * 2112 * 2);
  const size_t oW3h = take((size_t)2112 * 4224 * 2);  // quarter N-chunk of W3
  const size_t oW3l = take((size_t)2112 * 4224 * 2);
  const size_t oW4h = take((size_t)4224 * 2112 * 2);  // quarter K-slice of W4
  const size_t oW4l = take((size_t)4224 * 2112 * 2);
  const size_t oW5h = take((size_t)64 * 4224 * 2);
  const size_t oW5l = take((size_t)64 * 4224 * 2);
  const size_t fixed = off;

  // per-row bytes: X 640 + H1 8448 + H2 16896 + H3 8448 + ACC 16896 = 51328
  // (H4 overlays H2; QP overlays H1: 12*64*4 = 3072 B/row < 8448)
  int Mc = 8192;
  while (Mc > 256 && fixed + (size_t)Mc * 51328 + 4096 > ws_size) Mc >>= 1;

  const size_t oXh = take((size_t)Mc * 160 * 2);
  const size_t oXl = take((size_t)Mc * 160 * 2);
  const size_t oH1h = take((size_t)Mc * 2112 * 2);
  const size_t oH1l = take((size_t)Mc * 2112 * 2);
  const size_t oH2h = take((size_t)Mc * 4224 * 2);
  const size_t oH2l = take((size_t)Mc * 4224 * 2);
  const size_t oH3h = take((size_t)Mc * 2112 * 2);
  const size_t oH3l = take((size_t)Mc * 2112 * 2);
  const size_t oACC = take((size_t)Mc * 4224 * 4);

  _Float16* W1h = (_Float16*)(ws + oW1h);
  _Float16* W1l = (_Float16*)(ws + oW1l);
  _Float16* W2h = (_Float16*)(ws + oW2h);
  _Float16* W2l = (_Float16*)(ws + oW2l);
  _Float16* W3h = (_Float16*)(ws + oW3h);
  _Float16* W3l = (_Float16*)(ws + oW3l);
  _Float16* W4h = (_Float16*)(ws + oW4h);
  _Float16* W4l = (_Float16*)(ws + oW4l);
  _Float16* W5h = (_Float16*)(ws + oW5h);
  _Float16* W5l = (_Float16*)(ws + oW5l);
  _Float16* Xh = (_Float16*)(ws + oXh);
  _Float16* Xl = (_Float16*)(ws + oXl);
  _Float16* H1h = (_Float16*)(ws + oH1h);
  _Float16* H1l = (_Float16*)(ws + oH1l);
  _Float16* H2h = (_Float16*)(ws + oH2h);
  _Float16* H2l = (_Float16*)(ws + oH2l);
  _Float16* H3h = (_Float16*)(ws + oH3h);
  _Float16* H3l = (_Float16*)(ws + oH3l);
  float* ACC = (float*)(ws + oACC);
  _Float16* H4h = H2h;              // overlays H2 (dead after last L3)
  _Float16* H4l = H2l;
  float* QP = (float*)(ws + oH1h);  // overlays H1 (dead after L2)

  // persistent weight splits (W1 padded 132->160)
  split_w_kernel<<<dim3(1, 2112), 256, 0, stream>>>(w1, W1h, W1l, 132, 0, 132, 160);
  split_w_kernel<<<dim3(9, 4224), 256, 0, stream>>>(w2, W2h, W2l, 2112, 0, 2112, 2112);
  split_w_kernel<<<dim3(17, 64), 256, 0, stream>>>(wq, W5h, W5l, 4224, 0, 4224, 4224);

  const int NC = 8192 / Mc;
  const int GX = Mc / 256;
  for (int mc = 0; mc < NC; ++mc) {
    const float* st = state + (size_t)mc * Mc * 128;
    const float* pf = pref + (size_t)mc * Mc * 4;
    prep_x_kernel<<<dim3(Mc), 192, 0, stream>>>(st, pf, Xh, Xl);
    // L1: [Mc,160] x [2112,160]
    gemm3_kernel<<<dim3(GX, 17), 256, 0, stream>>>(Xh, Xl, W1h, W1l, b1, H1h, H1l,
                                                   nullptr, 160, 2112, 160, 0, 0, Mc);
    // L2: K=2112 -> N=4224
    gemm3_kernel<<<dim3(GX, 33), 256, 0, stream>>>(H1h, H1l, W2h, W2l, b2, H2h, H2l,
                                                   nullptr, 2112, 4224, 2112, 0, 0, Mc);
    // L3/L4 fused over 4 N-chunks of H3 (2112 each); ACC accumulates L4;
    // last chunk finalizes relu+b4 and writes split H4 planes (over H2).
    for (int c = 0; c < 4; ++c) {
      split_w_kernel<<<dim3(17, 2112), 256, 0, stream>>>(w3 + (size_t)c * 2112 * 4224, W3h,
                                                         W3l, 4224, 0, 4224, 4224);
      split_w_kernel<<<dim3(9, 4224), 256, 0, stream>>>(w4, W4h, W4l, 8448, c * 2112, 2112,
                                                        2112);
      gemm3_kernel<<<dim3(GX, 17), 256, 0, stream>>>(H2h, H2l, W3h, W3l, b3 + c * 2112,
                                                     H3h, H3l, nullptr, 4224, 2112, 4224,
                                                     0, 0, Mc);
      if (c < 3) {
        gemm3_kernel<<<dim3(GX, 33), 256, 0, stream>>>(H3h, H3l, W4h, W4l, nullptr, nullptr,
                                                       nullptr, ACC, 2112, 4224, 2112, 1,
                                                       c > 0 ? 1 : 0, Mc);
      } else {
        gemm3_kernel<<<dim3(GX, 33), 256, 0, stream>>>(H3h, H3l, W4h, W4l, b4, H4h, H4l,
                                                       ACC, 2112, 4224, 2112, 2, 0, Mc);
      }
    }
    // L5: [Mc,4224] x [64,4224], split-K=12 (kPerZ=352) -> QP fp32 partials
    gemm3_kernel<<<dim3(GX, 1, 12), 256, 0, stream>>>(H4h, H4l, W5h, W5l, nullptr, nullptr,
                                                      nullptr, QP, 4224, 64, 352, 1, 0, Mc);
    // reduce partials + bq, write q, envelope argmax -> hq
    finish_kernel<<<dim3(Mc / 128), 128, 0, stream>>>(QP, bq, pref, (float*)d_out,
                                                      mc * Mc, Mc);
  }
}